// Round 2
// baseline (9958.843 us; speedup 1.0000x reference)
//
#include <hip/hip_runtime.h>
#include <cstdint>

constexpr int BB = 128;   // batch
constexpr int SS = 512;   // source length
constexpr int DD = 512;   // hidden dim
constexpr int TT = 64;    // decode steps
constexpr int OO = 3;     // output dim

constexpr float C2LE = 2.8853900817779268f;  // 2*log2(e)

typedef __attribute__((ext_vector_type(8))) short bf16x8;
typedef __attribute__((ext_vector_type(4))) float f32x4;

__device__ __forceinline__ float tanh_fast(float x) {
  float e = __expf(2.0f * x);
  return 1.0f - 2.0f / (e + 1.0f);
}
__device__ __forceinline__ float sigmoid_fast(float x) {
  return 1.0f / (1.0f + __expf(-x));
}
__device__ __forceinline__ unsigned short f2bf(float f) {
  uint32_t u = __float_as_uint(f);
  uint32_t r = (u + 0x7FFFu + ((u >> 16) & 1u)) >> 16;  // RNE
  return (unsigned short)r;
}
__device__ __forceinline__ float2 bfx2(uint32_t u) {
  float2 r;
  r.x = __uint_as_float(u << 16);
  r.y = __uint_as_float(u & 0xFFFF0000u);
  return r;
}
__device__ __forceinline__ float fexp2(float x) {
#if __has_builtin(__builtin_amdgcn_exp2f)
  return __builtin_amdgcn_exp2f(x);
#else
  return exp2f(x);
#endif
}
__device__ __forceinline__ float frcp(float x) {
#if __has_builtin(__builtin_amdgcn_rcpf)
  return __builtin_amdgcn_rcpf(x);
#else
  return 1.0f / x;
#endif
}

// ---------------------------------------------------------------------------
// MFMA bf16 GEMM: Uk2 = bf16( C2LE * (e_bf @ Ua_bf^T + bu) )   [B*S x D]
// ---------------------------------------------------------------------------
__global__ __launch_bounds__(256) void gemm_uk_mfma(
    const unsigned short* __restrict__ A, const unsigned short* __restrict__ Bw,
    const float* __restrict__ bias, unsigned short* __restrict__ Uk) {
  __shared__ unsigned short Asb[128 * 40];
  __shared__ unsigned short Bsb[128 * 40];
  const int tid = threadIdx.x;
  const int m0 = blockIdx.y * 128, n0 = blockIdx.x * 128;
  const int w = tid >> 6, l = tid & 63;
  const int wr = w >> 1, wc = w & 1;
  const int lm = l & 15, kg = l >> 4;

  f32x4 acc[4][4] = {};

  for (int kc = 0; kc < 512; kc += 32) {
    uint4 av[2], bv[2];
#pragma unroll
    for (int p = 0; p < 2; ++p) {
      int u = tid + p * 256;
      int r = u >> 2, ko = (u & 3) * 8;
      av[p] = *(const uint4*)(A + (size_t)(m0 + r) * 512 + kc + ko);
      bv[p] = *(const uint4*)(Bw + (size_t)(n0 + r) * 512 + kc + ko);
    }
    __syncthreads();
#pragma unroll
    for (int p = 0; p < 2; ++p) {
      int u = tid + p * 256;
      int r = u >> 2, ko = (u & 3) * 8;
      *(uint4*)&Asb[r * 40 + ko] = av[p];
      *(uint4*)&Bsb[r * 40 + ko] = bv[p];
    }
    __syncthreads();
    bf16x8 af[4], bfr[4];
#pragma unroll
    for (int i = 0; i < 4; ++i) {
      af[i]  = *(const bf16x8*)&Asb[(wr * 64 + i * 16 + lm) * 40 + kg * 8];
      bfr[i] = *(const bf16x8*)&Bsb[(wc * 64 + i * 16 + lm) * 40 + kg * 8];
    }
#pragma unroll
    for (int i = 0; i < 4; ++i)
#pragma unroll
      for (int j = 0; j < 4; ++j)
        acc[i][j] = __builtin_amdgcn_mfma_f32_16x16x32_bf16(af[i], bfr[j],
                                                            acc[i][j], 0, 0, 0);
  }

  const int row_base = m0 + wr * 64;
  const int col_base = n0 + wc * 64;
#pragma unroll
  for (int j = 0; j < 4; ++j) {
    const int col = col_base + j * 16 + lm;
    const float bu = bias[col];
#pragma unroll
    for (int i = 0; i < 4; ++i) {
      const int r0 = row_base + i * 16 + kg * 4;
#pragma unroll
      for (int rr = 0; rr < 4; ++rr)
        Uk[(size_t)(r0 + rr) * 512 + col] = f2bf(C2LE * (acc[i][j][rr] + bu));
    }
  }
}

// fp32 -> bf16, 8 elems/thread
__global__ __launch_bounds__(256) void conv_bf(const float* __restrict__ in,
                                               unsigned short* __restrict__ outp) {
  size_t idx = ((size_t)blockIdx.x * 256 + threadIdx.x) * 8;
  const float4* p = (const float4*)(in + idx);
  float4 a = p[0], b = p[1];
  uint4 r;
  r.x = f2bf(a.x) | ((uint32_t)f2bf(a.y) << 16);
  r.y = f2bf(a.z) | ((uint32_t)f2bf(a.w) << 16);
  r.z = f2bf(b.x) | ((uint32_t)f2bf(b.y) << 16);
  r.w = f2bf(b.z) | ((uint32_t)f2bf(b.w) << 16);
  *(uint4*)(outp + idx) = r;
}

// Wcat packed uint32[512 k][1024 col-pairs]: col j<512 -> C2LE*Wa[j][k] (q2),
// col j>=512 -> W_hh[j-512][k] (gh).
__global__ void prep_wcat(const float* __restrict__ Wa,
                          const float* __restrict__ Whh,
                          uint32_t* __restrict__ Wcat) {
  int idx = blockIdx.x * 256 + threadIdx.x;  // 512*1024
  int k = idx >> 10, j2 = idx & 1023;
  int j0 = 2 * j2;
  float v0 = (j0 < DD) ? Wa[(size_t)j0 * DD + k] * C2LE
                       : Whh[(size_t)(j0 - DD) * DD + k];
  float v1 = (j0 + 1 < DD) ? Wa[(size_t)(j0 + 1) * DD + k] * C2LE
                           : Whh[(size_t)(j0 + 1 - DD) * DD + k];
  Wcat[idx] = (uint32_t)f2bf(v0) | ((uint32_t)f2bf(v1) << 16);
}

__global__ void prep_bcat(const float* __restrict__ ba,
                          const float* __restrict__ bhh,
                          float* __restrict__ bcat) {
  int j = blockIdx.x * 256 + threadIdx.x;  // 2048
  bcat[j] = (j < DD) ? ba[j] * C2LE : bhh[j - DD];
}

// Wih2 packed uint32[512 k][768 col-pairs]: cols of W_ih[:, :512]^T (bf16)
__global__ void prep_wih(const float* __restrict__ W_ih,
                         uint32_t* __restrict__ Wih2) {
  int idx = blockIdx.x * 256 + threadIdx.x;  // 512*768
  int k = idx / 768, j2 = idx % 768;
  int j0 = 2 * j2;
  float v0 = W_ih[(size_t)j0 * (DD + OO) + k];
  float v1 = W_ih[(size_t)(j0 + 1) * (DD + OO) + k];
  Wih2[(size_t)k * 768 + j2] = (uint32_t)f2bf(v0) | ((uint32_t)f2bf(v1) << 16);
}

// ---------------------------------------------------------------------------
// Pair barrier: epoch-counted arrive+spin on a per-pair device counter.
// Counter region is zeroed by hipMemsetAsync before each decode launch, so
// graph replays are safe. Both blocks of a pair execute identical sequences.
// ---------------------------------------------------------------------------
__device__ __forceinline__ void pbar(unsigned int* bp, unsigned int target) {
  __syncthreads();
  if (threadIdx.x == 0) {
    __threadfence();
    atomicAdd(bp, 1u);
    while (__hip_atomic_load(bp, __ATOMIC_ACQUIRE, __HIP_MEMORY_SCOPE_AGENT) <
           target)
      __builtin_amdgcn_s_sleep(1);
  }
  __syncthreads();
}

// D phase: [q2 | gh] = h @ Wcat + bcat, cols split by half; optional out-proj.
__device__ __forceinline__ void phase_qgh(
    int b, int half, int tid, bool doOut, int t,
    const float* __restrict__ hg, const uint32_t* __restrict__ Wcat,
    const float* __restrict__ bcat, float* __restrict__ q2g,
    float* __restrict__ ghg, const float* __restrict__ W_out,
    const float* __restrict__ b_out, float* __restrict__ out_d,
    float* h_s, float* pd_s) {
  if (tid < 512) h_s[tid] = hg[(size_t)b * DD + tid];
  __syncthreads();
  float ax = 0.f, ay = 0.f;
  {
    const int p = tid & 511, kb = tid >> 9;
    const int j2 = half * 512 + p;
    const uint32_t* wp = Wcat + (size_t)(kb * 256) * 1024 + j2;
    const float* hb = &h_s[kb * 256];
    for (int k0 = 0; k0 < 256; k0 += 4) {
      float4 hv = *(const float4*)&hb[k0];
      float2 w0 = bfx2(wp[(size_t)(k0 + 0) * 1024]);
      float2 w1 = bfx2(wp[(size_t)(k0 + 1) * 1024]);
      float2 w2 = bfx2(wp[(size_t)(k0 + 2) * 1024]);
      float2 w3 = bfx2(wp[(size_t)(k0 + 3) * 1024]);
      ax += hv.x * w0.x; ay += hv.x * w0.y;
      ax += hv.y * w1.x; ay += hv.y * w1.y;
      ax += hv.z * w2.x; ay += hv.z * w2.y;
      ax += hv.w * w3.x; ay += hv.w * w3.y;
    }
    if (kb) { pd_s[2 * p] = ax; pd_s[2 * p + 1] = ay; }
  }
  __syncthreads();
  if (tid < 512) {
    float gx = ax + pd_s[2 * tid];
    float gy = ay + pd_s[2 * tid + 1];
    const int j0 = 2 * (half * 512 + tid);
    gx += bcat[j0];
    gy += bcat[j0 + 1];
    if (j0 < DD) {
      q2g[(size_t)b * DD + j0] = gx;
      q2g[(size_t)b * DD + j0 + 1] = gy;
    } else {
      ghg[(size_t)b * 3 * DD + j0 - DD] = gx;
      ghg[(size_t)b * 3 * DD + j0 + 1 - DD] = gy;
    }
  }
  if (doOut && half == 0 && tid < 192) {
    const int wid = tid >> 6, ln = tid & 63;
    const float* wrow = W_out + (size_t)wid * DD;
    float acc = 0.f;
    for (int i = ln; i < DD; i += 64) acc += h_s[i] * wrow[i];
#pragma unroll
    for (int off = 32; off; off >>= 1) acc += __shfl_xor(acc, off);
    if (ln == 0) out_d[((size_t)b * TT + t) * OO + wid] = acc + b_out[wid];
  }
}

// ---------------------------------------------------------------------------
// Pair-split persistent decode: 2 blocks per batch (grid 256 = all CUs).
// Per-batch cross-block exchange via global + device-atomic pair barriers.
// ---------------------------------------------------------------------------
__global__ __launch_bounds__(1024) void decode_pair(
    const unsigned short* __restrict__ Uk2, const unsigned short* __restrict__ e_bf,
    const uint32_t* __restrict__ Wcat, const float* __restrict__ bcat,
    const uint32_t* __restrict__ Wih2, const float* __restrict__ b_ih,
    const float* __restrict__ W_ih, const float* __restrict__ e_last,
    const float* __restrict__ target, const float* __restrict__ Va_w,
    const float* __restrict__ W_out, const float* __restrict__ b_out,
    float* __restrict__ q2g, float* __restrict__ ctxp, float* __restrict__ ghg,
    float* __restrict__ stats, unsigned int* __restrict__ bar,
    float* __restrict__ out_d, float* __restrict__ hg /*== out_hT*/,
    float* __restrict__ out_attn) {
  const int blk = blockIdx.x;
  const int b = blk >> 1, half = blk & 1;
  const int tid = threadIdx.x;
  const int sbase = half * 256;  // this block's s-range base / d-range base
  unsigned int* bp = &bar[b];
  unsigned int bc = 0;

  __shared__ float qv_s[4 * 132];   // q2, quarter-padded (conflict-free)
  __shared__ float va_s[4 * 132];   // va, quarter-padded
  __shared__ float sc_s[256];       // local-half y = -2*score'
  __shared__ float w_s[256];        // local-half softmax weights
  __shared__ float red_s[32];
  __shared__ float part2[16 * 512]; // ctx partials [sg][c][dsl]
  __shared__ float ctx_s[512];
  __shared__ float gi_s[768];       // [gate][local d]
  __shared__ float h_s[512];
  __shared__ float pc_s[768];       // C kb-reduce
  __shared__ float pd_s[1024];      // D kb-reduce

  // ---- init: va cache (persists), h = e_last (own d-half)
  if (tid < 512) {
    float v = Va_w[tid];
    va_s[(tid >> 7) * 132 + (tid & 127)] = v;
  }
  if (tid < 256) {
    const int d = sbase + tid;
    hg[(size_t)b * DD + d] = e_last[(size_t)b * DD + d];
  }
  pbar(bp, 2 * (++bc));
  phase_qgh(b, half, tid, false, 0, hg, Wcat, bcat, q2g, ghg, W_out, b_out,
            out_d, h_s, pd_s);
  pbar(bp, 2 * (++bc));

  for (int t = 0; t < TT; ++t) {
    // ---- A: scores'[s] = sum_d va[d]/(1+2^(q2[d]+Uk2[b,s,d])), own s-half
    if (tid < 512) {
      float v = q2g[(size_t)b * DD + tid];
      qv_s[(tid >> 7) * 132 + (tid & 127)] = v;
    }
    __syncthreads();
    {
      const int sl = tid >> 2, qp = tid & 3;
      const uint4* up =
          (const uint4*)(Uk2 + ((size_t)b * SS + sbase + sl) * DD + qp * 128);
      const float* qb = &qv_s[qp * 132];
      const float* vb = &va_s[qp * 132];
      float acc = 0.f;
#pragma unroll 4
      for (int j = 0; j < 16; ++j) {
        uint4 u = up[j];
        float4 q0 = *(const float4*)&qb[j * 8];
        float4 q1 = *(const float4*)&qb[j * 8 + 4];
        float4 v0 = *(const float4*)&vb[j * 8];
        float4 v1 = *(const float4*)&vb[j * 8 + 4];
        float2 e0 = bfx2(u.x), e1 = bfx2(u.y), e2 = bfx2(u.z), e3 = bfx2(u.w);
        acc += v0.x * frcp(1.f + fexp2(q0.x + e0.x));
        acc += v0.y * frcp(1.f + fexp2(q0.y + e0.y));
        acc += v0.z * frcp(1.f + fexp2(q0.z + e1.x));
        acc += v0.w * frcp(1.f + fexp2(q0.w + e1.y));
        acc += v1.x * frcp(1.f + fexp2(q1.x + e2.x));
        acc += v1.y * frcp(1.f + fexp2(q1.y + e2.y));
        acc += v1.z * frcp(1.f + fexp2(q1.z + e3.x));
        acc += v1.w * frcp(1.f + fexp2(q1.w + e3.y));
      }
      acc += __shfl_xor(acc, 1);
      acc += __shfl_xor(acc, 2);
      if (qp == 0) sc_s[sl] = -2.f * acc;  // softmax logit (up to +const)
    }
    __syncthreads();
    // local softmax stats (m, l) over own 256
    {
      float v = (tid < 256) ? sc_s[tid] : -3.0e38f;
      float m = v;
#pragma unroll
      for (int off = 32; off; off >>= 1) m = fmaxf(m, __shfl_xor(m, off));
      if ((tid & 63) == 0) red_s[tid >> 6] = m;
      __syncthreads();
      float gm = fmaxf(fmaxf(red_s[0], red_s[1]), fmaxf(red_s[2], red_s[3]));
      float e = (tid < 256) ? __expf(v - gm) : 0.f;
      float sm = e;
#pragma unroll
      for (int off = 32; off; off >>= 1) sm += __shfl_xor(sm, off);
      if ((tid & 63) == 0) red_s[16 + (tid >> 6)] = sm;
      __syncthreads();
      if (tid == 0) {
        stats[b * 4 + half * 2] = gm;
        stats[b * 4 + half * 2 + 1] =
            red_s[16] + red_s[17] + red_s[18] + red_s[19];
      }
    }
    pbar(bp, 2 * (++bc));

    // ---- B: finalize softmax from exchanged stats; ctx partial (own s-half)
    {
      const float m0 = stats[b * 4 + 0], l0 = stats[b * 4 + 1];
      const float m1 = stats[b * 4 + 2], l1 = stats[b * 4 + 3];
      const float M = fmaxf(m0, m1);
      const float invZ = frcp(l0 * __expf(m0 - M) + l1 * __expf(m1 - M));
      if (tid < 256) {
        float wv = __expf(sc_s[tid] - M) * invZ;
        w_s[tid] = wv;
        out_attn[((size_t)b * TT + t) * SS + sbase + tid] = wv;
      }
    }
    __syncthreads();
    {
      const int dsl = tid & 63, sg = tid >> 6;
      const unsigned short* eb =
          e_bf + ((size_t)b * SS + sbase + sg * 16) * DD + dsl * 8;
      float a0 = 0.f, a1 = 0.f, a2 = 0.f, a3 = 0.f;
      float a4 = 0.f, a5 = 0.f, a6 = 0.f, a7 = 0.f;
#pragma unroll 4
      for (int si = 0; si < 16; ++si) {
        uint4 u = *(const uint4*)(eb + (size_t)si * DD);
        float ws = w_s[sg * 16 + si];
        float2 p0 = bfx2(u.x), p1 = bfx2(u.y), p2 = bfx2(u.z), p3 = bfx2(u.w);
        a0 += ws * p0.x; a1 += ws * p0.y;
        a2 += ws * p1.x; a3 += ws * p1.y;
        a4 += ws * p2.x; a5 += ws * p2.y;
        a6 += ws * p3.x; a7 += ws * p3.y;
      }
      part2[sg * 512 + 0 * 64 + dsl] = a0;
      part2[sg * 512 + 1 * 64 + dsl] = a1;
      part2[sg * 512 + 2 * 64 + dsl] = a2;
      part2[sg * 512 + 3 * 64 + dsl] = a3;
      part2[sg * 512 + 4 * 64 + dsl] = a4;
      part2[sg * 512 + 5 * 64 + dsl] = a5;
      part2[sg * 512 + 6 * 64 + dsl] = a6;
      part2[sg * 512 + 7 * 64 + dsl] = a7;
    }
    __syncthreads();
    if (tid < 512) {
      const int c = tid >> 6, dsl = tid & 63;
      float r = 0.f;
#pragma unroll
      for (int sg = 0; sg < 16; ++sg) r += part2[sg * 512 + c * 64 + dsl];
      ctxp[(size_t)b * 1024 + half * 512 + dsl * 8 + c] = r;
    }
    pbar(bp, 2 * (++bc));

    // ---- C: gi = ctx @ Wih2 (own col-half: 3 gates x own d-range) + GRU
    if (tid < 512)
      ctx_s[tid] = ctxp[(size_t)b * 1024 + tid] + ctxp[(size_t)b * 1024 + 512 + tid];
    __syncthreads();
    float cx = 0.f, cy = 0.f;
    {
      if (tid < 768) {
        const int kb = (tid >= 384), p = tid - kb * 384;
        const int g = p >> 7, pp = p & 127;
        const int j2 = g * 256 + half * 128 + pp;
        const uint32_t* wp = Wih2 + (size_t)(kb * 256) * 768 + j2;
        const float* cb = &ctx_s[kb * 256];
        for (int k0 = 0; k0 < 256; k0 += 4) {
          float4 cv = *(const float4*)&cb[k0];
          float2 w0 = bfx2(wp[(size_t)(k0 + 0) * 768]);
          float2 w1 = bfx2(wp[(size_t)(k0 + 1) * 768]);
          float2 w2 = bfx2(wp[(size_t)(k0 + 2) * 768]);
          float2 w3 = bfx2(wp[(size_t)(k0 + 3) * 768]);
          cx += cv.x * w0.x; cy += cv.x * w0.y;
          cx += cv.y * w1.x; cy += cv.y * w1.y;
          cx += cv.z * w2.x; cy += cv.z * w2.y;
          cx += cv.w * w3.x; cy += cv.w * w3.y;
        }
        if (kb) { pc_s[2 * p] = cx; pc_s[2 * p + 1] = cy; }
      }
    }
    __syncthreads();
    if (tid < 384) {
      const int g = tid >> 7, pp = tid & 127;
      float gx = cx + pc_s[2 * tid];
      float gy = cy + pc_s[2 * tid + 1];
      const int colg = g * 512 + half * 256 + 2 * pp;
      float2 gv;
      gv.x = gx + b_ih[colg];
      gv.y = gy + b_ih[colg + 1];
      *(float2*)&gi_s[g * 256 + 2 * pp] = gv;
    }
    __syncthreads();
    if (tid < 256) {  // GRU pointwise, own d-half
      const int dl = tid, d = sbase + dl;
      float x0 = 0.f, x1 = 0.f, x2 = 0.f;
      if (t > 0) {
        const float* xp = target + ((size_t)b * TT + (t - 1)) * OO;
        x0 = xp[0]; x1 = xp[1]; x2 = xp[2];
      }
      const float* w0 = W_ih + (size_t)d * (DD + OO) + DD;
      const float* w1 = W_ih + (size_t)(DD + d) * (DD + OO) + DD;
      const float* w2p = W_ih + (size_t)(2 * DD + d) * (DD + OO) + DD;
      float ir  = gi_s[dl]        + x0 * w0[0] + x1 * w0[1] + x2 * w0[2];
      float iz  = gi_s[256 + dl]  + x0 * w1[0] + x1 * w1[1] + x2 * w1[2];
      float in_ = gi_s[512 + dl]  + x0 * w2p[0] + x1 * w2p[1] + x2 * w2p[2];
      const float* ghb = ghg + (size_t)b * 3 * DD;
      float r = sigmoid_fast(ir + ghb[d]);
      float z = sigmoid_fast(iz + ghb[DD + d]);
      float n = tanh_fast(in_ + r * ghb[2 * DD + d]);
      float hp = hg[(size_t)b * DD + d];
      hg[(size_t)b * DD + d] = (1.f - z) * n + z * hp;  // hg == out_hT
    }
    pbar(bp, 2 * (++bc));

    // ---- D: next-step [q2|gh] (own col-half) + out-proj (half 0)
    phase_qgh(b, half, tid, true, t, hg, Wcat, bcat, q2g, ghg, W_out, b_out,
              out_d, h_s, pd_s);
    pbar(bp, 2 * (++bc));
  }
}

// ---------------------------------------------------------------------------
extern "C" void kernel_launch(void* const* d_in, const int* in_sizes, int n_in,
                              void* d_out, int out_size, void* d_ws, size_t ws_size,
                              hipStream_t stream) {
  const float* e_all  = (const float*)d_in[0];
  const float* e_last = (const float*)d_in[1];
  const float* target = (const float*)d_in[2];
  const float* Wa     = (const float*)d_in[3];
  const float* ba     = (const float*)d_in[4];
  const float* Ua     = (const float*)d_in[5];
  const float* bu     = (const float*)d_in[6];
  const float* Va_w   = (const float*)d_in[7];
  const float* W_ih   = (const float*)d_in[9];
  const float* b_ih   = (const float*)d_in[10];
  const float* W_hh   = (const float*)d_in[11];
  const float* b_hh   = (const float*)d_in[12];
  const float* W_out  = (const float*)d_in[13];
  const float* b_out  = (const float*)d_in[14];

  float* out      = (float*)d_out;
  float* out_d    = out;                         // [B,T,3]
  float* out_hT   = out + (size_t)BB * TT * OO;  // [1,B,D]  (doubles as h)
  float* out_attn = out_hT + (size_t)BB * DD;    // [B,T,S]

  // Workspace layout (139,471,360 B <= 139,479,040 B proven-safe):
  //   0         Uk2   67,108,864
  //   67108864  e_bf  67,108,864
  //   134217728 Wcat   2,097,152
  //   136314880 Wih2   1,572,864
  //   137887744 bcat       8,192
  //   137895936 q2g      262,144   } decode-only; Ua_bf (524,288,
  //   138158080 ctxp     524,288   } prologue-only) aliases q2g+ctxp[0:256K]
  //   138682368 ghg      786,432
  //   139468800 stats      2,048
  //   139470848 bar          512
  char* wsB = (char*)d_ws;
  unsigned short* Uk2   = (unsigned short*)wsB;
  unsigned short* e_bfp = (unsigned short*)(wsB + 67108864);
  uint32_t* Wcat = (uint32_t*)(wsB + 134217728);
  uint32_t* Wih2 = (uint32_t*)(wsB + 136314880);
  float* bcat    = (float*)(wsB + 137887744);
  float* q2g     = (float*)(wsB + 137895936);
  float* ctxp    = (float*)(wsB + 138158080);
  float* ghg     = (float*)(wsB + 138682368);
  float* stats   = (float*)(wsB + 139468800);
  unsigned int* bar = (unsigned int*)(wsB + 139470848);
  unsigned short* Ua_bf = (unsigned short*)(wsB + 137895936);  // prologue alias

  prep_wcat<<<(DD * 1024) / 256, 256, 0, stream>>>(Wa, W_hh, Wcat);
  prep_bcat<<<2048 / 256, 256, 0, stream>>>(ba, b_hh, bcat);
  prep_wih<<<(DD * 768) / 256, 256, 0, stream>>>(W_ih, Wih2);
  conv_bf<<<(BB * SS * DD) / (8 * 256), 256, 0, stream>>>(e_all, e_bfp);
  conv_bf<<<(DD * DD) / (8 * 256), 256, 0, stream>>>(Ua, Ua_bf);
  gemm_uk_mfma<<<dim3(DD / 128, (BB * SS) / 128), 256, 0, stream>>>(
      e_bfp, Ua_bf, bu, Uk2);

  hipMemsetAsync(bar, 0, BB * sizeof(unsigned int), stream);

  decode_pair<<<2 * BB, 1024, 0, stream>>>(
      Uk2, e_bfp, Wcat, bcat, Wih2, b_ih, W_ih, e_last, target, Va_w,
      W_out, b_out, q2g, ctxp, ghg, stats, bar, out_d, out_hT, out_attn);
}